// Round 8
// baseline (289.092 us; speedup 1.0000x reference)
//
#include <hip/hip_runtime.h>

#define BQ   8
#define NQ   100
#define HWP  65536
#define TILE 128
#define KS   256        // fp32 cols staged per pass -> 1KB contiguous per row
#define NCC  32         // chunks per batch -> grid 256
#define NIT  8          // (HWP/NCC)/KS
#define LROW 256        // shorts per LDS row (KS bf16)
#define JR   13         // rows per wave (rows w+8j; 100 real rows)

typedef float  f32x4  __attribute__((ext_vector_type(4)));
typedef __bf16 bf16x8 __attribute__((ext_vector_type(8)));

__device__ __forceinline__ uint32_t pk2(float a, float b) {
    // RNE fp32 -> bf16, packed pair
    uint32_t ua = __builtin_bit_cast(uint32_t, a);
    uint32_t ub = __builtin_bit_cast(uint32_t, b);
    ua += 0x7FFFu + ((ua >> 16) & 1u);
    ub += 0x7FFFu + ((ub >> 16) & 1u);
    return (ua >> 16) | (ub & 0xFFFF0000u);
}

// One block = (batch, 2048-col chunk). 8 passes; per pass each WAVE reads
// whole 1KB row-segments (lane l -> float4 at base + l*16B): one DRAM page
// activation per 1KB (R7's win). NEW vs R7: next-pass loads are issued
// immediately after the current pass's convert -- before any barrier -- so
// the HBM pipe stays saturated through convert/write/compute instead of
// idling ~2-3us per pass. Budgeted under launch_bounds(512,2): 256-VGPR cap.
__global__ __launch_bounds__(512, 2) void matcher_gemm(
    const float* __restrict__ mp, const float* __restrict__ mg,
    float* __restrict__ dotp, float* __restrict__ normA, float* __restrict__ normB)
{
    __shared__ __align__(16) unsigned short ldsA[TILE * LROW]; // 64 KiB
    __shared__ __align__(16) unsigned short ldsB[TILE * LROW]; // 64 KiB

    const int blk  = blockIdx.x;
    const int b    = blk / NCC;
    const int slot = blk - b * NCC;
    const int p0   = slot * (NIT * KS);

    const int t    = threadIdx.x;
    const int lane = t & 63;
    const int w    = t >> 6;      // wave 0..7
    const int wr   = w >> 1;      // 0..3 -> 32-row strip of C
    const int wc   = w & 1;       // 0..1 -> 64-col strip of C

    // zero the padding rows (100..127) once; never rewritten
    for (int i = t; i < (TILE - NQ) * LROW / 8; i += 512) {
        const int off = NQ * LROW + i * 8;
        *(uint4*)(ldsA + off) = uint4{0, 0, 0, 0};
        *(uint4*)(ldsB + off) = uint4{0, 0, 0, 0};
    }

    const float* Ag = mp + (size_t)b * NQ * HWP;
    const float* Bg = mg + (size_t)b * NQ * HWP;

    f32x4 acc[2][4] = {};
    float nsA[JR], nsB[JR];
    #pragma unroll
    for (int j = 0; j < JR; ++j) { nsA[j] = 0.f; nsB[j] = 0.f; }

    // LDS write offset (shorts) within a row: 16B slot = (lane>>1) ^ (w&7)
    // (owned rows all have row&7 == w&7), lane parity picks the 8B half
    const int wofs = (((lane >> 1) ^ (w & 7)) << 3) + (lane & 1) * 4;

    // staging and packed registers (static indexing throughout — rule #20)
    float4 vA[JR], vB[JR];
    uint2  pA[JR], pB[JR];

    // prologue: issue pass-0 loads
    {
        const int cb = p0 + lane * 4;
        #pragma unroll
        for (int j = 0; j < JR; ++j) {
            const int r = w + 8 * j;
            vA[j] = (r < NQ) ? *(const float4*)(Ag + (size_t)r * HWP + cb)
                             : make_float4(0.f, 0.f, 0.f, 0.f);
            vB[j] = (r < NQ) ? *(const float4*)(Bg + (size_t)r * HWP + cb)
                             : make_float4(0.f, 0.f, 0.f, 0.f);
        }
    }

    #pragma unroll 1
    for (int it = 0; it < NIT; ++it) {
        // ---- convert current pass into packed regs + accumulate norms
        //      (compiler inserts the vmcnt waits on vA/vB here)
        #pragma unroll
        for (int j = 0; j < JR; ++j) {
            nsA[j] += vA[j].x*vA[j].x + vA[j].y*vA[j].y + vA[j].z*vA[j].z + vA[j].w*vA[j].w;
            pA[j].x = pk2(vA[j].x, vA[j].y);
            pA[j].y = pk2(vA[j].z, vA[j].w);
            nsB[j] += vB[j].x*vB[j].x + vB[j].y*vB[j].y + vB[j].z*vB[j].z + vB[j].w*vB[j].w;
            pB[j].x = pk2(vB[j].x, vB[j].y);
            pB[j].y = pk2(vB[j].z, vB[j].w);
        }

        // ---- issue NEXT pass's loads now: in flight through write+compute
        if (it + 1 < NIT) {
            const int cb = p0 + (it + 1) * KS + lane * 4;
            #pragma unroll
            for (int j = 0; j < JR; ++j) {
                const int r = w + 8 * j;
                vA[j] = (r < NQ) ? *(const float4*)(Ag + (size_t)r * HWP + cb)
                                 : make_float4(0.f, 0.f, 0.f, 0.f);
                vB[j] = (r < NQ) ? *(const float4*)(Bg + (size_t)r * HWP + cb)
                                 : make_float4(0.f, 0.f, 0.f, 0.f);
            }
        }

        // ---- previous pass's ds_reads are consumed (lgkmcnt drained by
        //      their MFMA uses); barrier, then overwrite the single buffer
        __builtin_amdgcn_s_barrier();
        #pragma unroll
        for (int j = 0; j < JR; ++j) {
            const int r = w + 8 * j;
            if (r < NQ) {
                *(uint2*)(ldsA + r * LROW + wofs) = pA[j];
                *(uint2*)(ldsB + r * LROW + wofs) = pB[j];
            }
        }
        asm volatile("s_waitcnt lgkmcnt(0)" ::: "memory"); // my writes committed
        __builtin_amdgcn_s_barrier();                      // all staging visible

        // ---- compute: 8 K-steps of MFMA over the staged 256 columns
        #pragma unroll
        for (int kk = 0; kk < 8; ++kk) {
            bf16x8 af[2];
            bf16x8 bfv[4];
            #pragma unroll
            for (int m = 0; m < 2; ++m) {
                const int r  = wr * 32 + m * 16 + (lane & 15);
                const int sl = (kk * 4 + (lane >> 4)) ^ (r & 7);
                af[m] = *(const bf16x8*)(ldsA + r * LROW + sl * 8);
            }
            #pragma unroll
            for (int n = 0; n < 4; ++n) {
                const int r  = wc * 64 + n * 16 + (lane & 15);
                const int sl = (kk * 4 + (lane >> 4)) ^ (r & 7);
                bfv[n] = *(const bf16x8*)(ldsB + r * LROW + sl * 8);
            }
            #pragma unroll
            for (int m = 0; m < 2; ++m)
                #pragma unroll
                for (int n = 0; n < 4; ++n)
                    acc[m][n] = __builtin_amdgcn_mfma_f32_16x16x32_bf16(
                        af[m], bfv[n], acc[m][n], 0, 0, 0);
        }
    }

    // final per-row norm reduction: full-wave shfl tree per owned row
    #pragma unroll
    for (int j = 0; j < JR; ++j) {
        const int r = w + 8 * j;
        float sa = nsA[j], sb = nsB[j];
        #pragma unroll
        for (int m = 1; m < 64; m <<= 1) {
            sa += __shfl_xor(sa, m);
            sb += __shfl_xor(sb, m);
        }
        if (lane == 0 && r < NQ) {
            normA[(size_t)blk * TILE + r] = sa;
            normB[(size_t)blk * TILE + r] = sb;
        }
    }

    // C/D layout (HW-verified): col = lane&15, row = (lane>>4)*4 + reg
    float* dp = dotp + (size_t)blk * (TILE * TILE);
    const int ccol = lane & 15;
    const int crow = (lane >> 4) * 4;
    #pragma unroll
    for (int m = 0; m < 2; ++m) {
        #pragma unroll
        for (int n = 0; n < 4; ++n) {
            const int gr = wr * 32 + m * 16 + crow;
            const int gc = wc * 64 + n * 16 + ccol;
            #pragma unroll
            for (int j = 0; j < 4; ++j)
                dp[(size_t)(gr + j) * TILE + gc] = acc[m][n][j];
        }
    }
}

// Reduce chunk partials, apply class-agreement term and dice division.
__global__ __launch_bounds__(256) void matcher_finalize(
    const float* __restrict__ y_p, const float* __restrict__ y_gt,
    const float* __restrict__ dotp, const float* __restrict__ normA,
    const float* __restrict__ normB, float* __restrict__ out)
{
    __shared__ float sA[TILE];
    __shared__ float sB[TILE];
    const int b    = blockIdx.x >> 4;
    const int part = blockIdx.x & 15;
    const int t    = threadIdx.x;

    if (t < TILE) {
        float s = 0.f;
        for (int c = 0; c < NCC; ++c) s += normA[(size_t)(b * NCC + c) * TILE + t];
        sA[t] = s;
    } else {
        float s = 0.f;
        for (int c = 0; c < NCC; ++c) s += normB[(size_t)(b * NCC + c) * TILE + (t - TILE)];
        sB[t - TILE] = s;
    }
    __syncthreads();

    for (int i = t; i < 625; i += 256) {
        const int idx = part * 625 + i;           // 0..9999 within batch
        const int n = idx / 100;
        const int k = idx - n * 100;
        float dot = 0.f;
        for (int c = 0; c < NCC; ++c)
            dot += dotp[(size_t)(b * NCC + c) * (TILE * TILE) + n * TILE + k];
        const float yp = y_p[b * NQ + n];
        const float yg = y_gt[b * NQ + k];
        const float t1 = yp * yg + (1.f - yp) * (1.f - yg);
        out[(size_t)b * (NQ * NQ) + idx] = t1 * (2.f * dot) / (sA[n] + sB[k]);
    }
}

extern "C" void kernel_launch(void* const* d_in, const int* in_sizes, int n_in,
                              void* d_out, int out_size, void* d_ws, size_t ws_size,
                              hipStream_t stream)
{
    const float* y_p  = (const float*)d_in[0];
    const float* y_gt = (const float*)d_in[1];
    const float* m_p  = (const float*)d_in[2];
    const float* m_gt = (const float*)d_in[3];
    float* out = (float*)d_out;

    float* dotp  = (float*)d_ws;    // 17 MB at NCC=32 (fits, per R1/R4)
    float* normA = dotp + (size_t)BQ * NCC * TILE * TILE;
    float* normB = normA + (size_t)BQ * NCC * TILE;

    matcher_gemm<<<dim3(BQ * NCC), dim3(512), 0, stream>>>(
        m_p, m_gt, dotp, normA, normB);
    matcher_finalize<<<dim3(BQ * 16), dim3(256), 0, stream>>>(
        y_p, y_gt, dotp, normA, normB, out);
}